// Round 1
// baseline (449.020 us; speedup 1.0000x reference)
//
#include <hip/hip_runtime.h>
#include <math.h>

#define PI_F 3.14159265358979323846f

// ---- output layout (flat float offsets, return order) ----
#define OUT_OUTPUT   0            // (64,4096,4)       = 1,048,576
#define OUT_BLOCKS   1048576      // (64,4096,16,16)   = 67,108,864
#define OUT_MU       68157440     // (64,1,2,1)        = 128
#define OUT_UG       68157568    // (64,1,2)           = 128
#define OUT_THETA    68157696    // (64,2,3)           = 384
// total 68,158,080

// ---- workspace layout (flat float offsets) ----
#define WS_A   0          // per block float4 {v1x, v1y, L1/L2-1, block_mean} : 262144*4
#define WS_B   1048576    // per block float4 {S0, gS1x, gS1y, 0}             : 262144*4
#define WS_IMG 2097152    // per image S0[64]
#define WS_M   2097216    // per image float4 {m00, m01, m11, 0} : 64*4
// total ~8.4 MB

// Kernel 1: stream x -> blocks (transpose via LDS), per-16x16-block moments + eigensolve.
// grid (4 colstrips, 64 rowstrips, 64 images), 256 threads.
__global__ __launch_bounds__(256) void k1_blocks(const float* __restrict__ x,
                                                 float* __restrict__ out,
                                                 float* __restrict__ ws) {
    // 16 image-blocks, each stored as 16 rows x 16 cols; stride 264 (pad 8 floats)
    // gives full-bank coverage for both b128 phases and conflict-free b32 moment reads.
    __shared__ float lds[16 * 264];
    const int t = threadIdx.x;
    const int colstrip = blockIdx.x;   // 0..3  (256 cols each)
    const int rowstrip = blockIdx.y;   // 0..63 (16 rows each) == block-row by
    const int b = blockIdx.z;          // image

    // ---- Phase A: coalesced read of 16x256 strip into LDS (block-major) ----
    const float4* x4 = reinterpret_cast<const float4*>(x)
                     + (size_t)b * 262144 + (size_t)rowstrip * 4096 + colstrip * 64;
    #pragma unroll
    for (int i = 0; i < 4; ++i) {
        int pos4 = i * 256 + t;          // strip float4 index, row-major
        int row  = pos4 >> 6;            // /64 float4 per row
        int col4 = pos4 & 63;
        float4 v = x4[row * 256 + col4];
        int ib = col4 >> 2;              // image-block within strip (0..15)
        int c4 = (col4 & 3) << 2;        // col within block (0,4,8,12)
        *reinterpret_cast<float4*>(&lds[ib * 264 + row * 16 + c4]) = v;
    }
    __syncthreads();

    // ---- Phase B: coalesced write of blocks output ----
    float* outB = out + OUT_BLOCKS
                + ((size_t)b * 4096 + rowstrip * 64 + colstrip * 16) * 256;
    #pragma unroll
    for (int i = 0; i < 4; ++i) {
        int pos4 = i * 256 + t;
        int ib  = pos4 >> 6;             // block index within strip
        int off = (pos4 & 63) << 2;      // float offset within block (0..252)
        float4 v = *reinterpret_cast<const float4*>(&lds[ib * 264 + off]);
        reinterpret_cast<float4*>(outB)[pos4] = v;
    }

    // ---- Phase C: moments. 16 lanes per image-block, lane = column. ----
    const int ib = t >> 4;   // 0..15
    const int c  = t & 15;
    float s0 = 0.f, s1y = 0.f, s2yy = 0.f;
    #pragma unroll
    for (int r = 0; r < 16; ++r) {
        float v  = lds[ib * 264 + r * 16 + c];
        float rf = (float)r;
        s0   += v;
        s1y  += rf * v;
        s2yy += rf * rf * v;
    }
    float cf   = (float)c;
    float s1x  = cf * s0;
    float s2xx = cf * cf * s0;
    float s2xy = cf * s1y;
    // butterfly reduce across the 16 lanes of this image-block
    #pragma unroll
    for (int m = 1; m <= 8; m <<= 1) {
        s0   += __shfl_xor(s0,   m);
        s1x  += __shfl_xor(s1x,  m);
        s1y  += __shfl_xor(s1y,  m);
        s2xx += __shfl_xor(s2xx, m);
        s2yy += __shfl_xor(s2yy, m);
        s2xy += __shfl_xor(s2xy, m);
    }
    if (c == 0) {
        float denom = s0 + 1e-8f;
        float inv   = 1.0f / denom;
        float mu_x = s1x * inv, mu_y = s1y * inv;
        float cxx = (s2xx - 2.f * mu_x * s1x + mu_x * mu_x * s0) * inv;
        float cyy = (s2yy - 2.f * mu_y * s1y + mu_y * mu_y * s0) * inv;
        float cxy = (s2xy - mu_x * s1y - mu_y * s1x + mu_x * mu_y * s0) * inv;
        float tr  = cxx + cyy;
        float det = cxx * cyy - cxy * cxy;
        float disc = sqrtf(fmaxf(tr * tr - 4.f * det, 0.f));
        float L1 = 0.5f * (tr + disc), L2 = 0.5f * (tr - disc);
        float v1x = L1 - cyy, v1y = cxy;
        float n = fmaxf(sqrtf(v1x * v1x + v1y * v1y), 1e-12f);
        v1x /= n; v1y /= n;
        float rm1 = L1 / L2 - 1.0f;

        int l = rowstrip * 64 + colstrip * 16 + ib;   // block index within image
        size_t gbl = (size_t)b * 4096 + l;
        out[OUT_OUTPUT + gbl * 4 + 0] = mu_x;
        out[OUT_OUTPUT + gbl * 4 + 1] = mu_y;

        float X0 = (float)(colstrip * 256 + ib * 16);
        float Y0 = (float)(rowstrip * 16);
        float4 wa = make_float4(v1x, v1y, rm1, s0 * (1.f / 256.f));
        float4 wb = make_float4(s0, s1x + X0 * s0, s1y + Y0 * s0, 0.f);
        reinterpret_cast<float4*>(ws + WS_A)[gbl] = wa;
        reinterpret_cast<float4*>(ws + WS_B)[gbl] = wb;
    }
}

// Kernel 2: per-image global first moments -> mu_global, imgS0. grid 64 x 256.
__global__ __launch_bounds__(256) void k2_global(float* __restrict__ out,
                                                 float* __restrict__ ws) {
    __shared__ float red[12];
    const int b = blockIdx.x;
    const int t = threadIdx.x;
    float s0 = 0.f, gx = 0.f, gy = 0.f;
    const float4* wb = reinterpret_cast<const float4*>(ws + WS_B) + (size_t)b * 4096;
    #pragma unroll
    for (int k = 0; k < 16; ++k) {
        float4 v = wb[t + k * 256];
        s0 += v.x; gx += v.y; gy += v.z;
    }
    #pragma unroll
    for (int m = 1; m <= 32; m <<= 1) {
        s0 += __shfl_xor(s0, m);
        gx += __shfl_xor(gx, m);
        gy += __shfl_xor(gy, m);
    }
    int w = t >> 6;
    if ((t & 63) == 0) { red[w] = s0; red[4 + w] = gx; red[8 + w] = gy; }
    __syncthreads();
    if (t == 0) {
        float S0 = red[0] + red[1] + red[2] + red[3];
        float GX = red[4] + red[5] + red[6] + red[7];
        float GY = red[8] + red[9] + red[10] + red[11];
        float inv = 1.0f / (S0 + 1e-8f);
        out[OUT_MU + b * 2 + 0] = GX * inv;
        out[OUT_MU + b * 2 + 1] = GY * inv;
        ws[WS_IMG + b] = S0;
    }
}

// Kernel 3: conf/orient + per-image M reduction. grid 64 x 256.
__global__ __launch_bounds__(256) void k3_orient(float* __restrict__ out,
                                                 float* __restrict__ ws) {
    __shared__ float red[12];
    const int b = blockIdx.x;
    const int t = threadIdx.x;
    float tot = 0.f;
    #pragma unroll
    for (int k = 0; k < 64; ++k) tot += ws[WS_IMG + k];     // L2-cached broadcast
    float invmean = 67108864.0f / tot;                       // 1/mean(x)
    float m00 = 0.f, m01 = 0.f, m11 = 0.f;
    const float4* wa = reinterpret_cast<const float4*>(ws + WS_A) + (size_t)b * 4096;
    #pragma unroll
    for (int k = 0; k < 16; ++k) {
        int l = t + k * 256;
        float4 v = wa[l];
        float z = v.z * (v.w * invmean);
        float conf = 20.f * (1.f / (1.f + expf(-z)) - 0.5f);
        float ox = v.x * conf, oy = v.y * conf;
        size_t gbl = (size_t)b * 4096 + l;
        *reinterpret_cast<float2*>(&out[OUT_OUTPUT + gbl * 4 + 2]) = make_float2(ox, oy);
        m00 += ox * ox; m01 += ox * oy; m11 += oy * oy;
    }
    #pragma unroll
    for (int m = 1; m <= 32; m <<= 1) {
        m00 += __shfl_xor(m00, m);
        m01 += __shfl_xor(m01, m);
        m11 += __shfl_xor(m11, m);
    }
    int w = t >> 6;
    if ((t & 63) == 0) { red[w] = m00; red[4 + w] = m01; red[8 + w] = m11; }
    __syncthreads();
    if (t == 0) {
        float M00 = red[0] + red[1] + red[2] + red[3];
        float M01 = red[4] + red[5] + red[6] + red[7];
        float M11 = red[8] + red[9] + red[10] + red[11];
        reinterpret_cast<float4*>(ws + WS_M)[b] = make_float4(M00, M01, M11, 0.f);
    }
}

// Kernel 4: U_global + theta. 1 block x 64 threads (thread = image).
__global__ void k4_theta(float* __restrict__ out, const float* __restrict__ ws) {
    int b = threadIdx.x;
    if (b >= 64) return;
    float4 M = reinterpret_cast<const float4*>(ws + WS_M)[b];
    float T = M.x + M.z;
    float D = M.x * M.z - M.y * M.y;
    float L1g = 0.5f * (T + sqrtf(fmaxf(T * T - 4.f * D, 0.f)));
    float vx = L1g - M.z, vy = M.y;
    float n = fmaxf(sqrtf(vx * vx + vy * vy), 1e-12f);
    float Vx = vx / n, Vy = vy / n;
    out[OUT_UG + b * 2 + 0] = Vx;
    out[OUT_UG + b * 2 + 1] = Vy;
    float rot = fmodf(atan2f(Vy, Vx + 1e-4f) + 2.f * PI_F, PI_F);
    float diff = 0.5f * PI_F - rot;
    float cc = cosf(diff), ssn = sinf(diff);
    float mu_x = out[OUT_MU + b * 2 + 0];
    float mu_y = out[OUT_MU + b * 2 + 1];
    float mtx = (mu_x * (1.f / 1024.f) - 0.5f) * 2.f;
    float mty = (mu_y * (1.f / 1024.f) - 0.5f) * (-2.f);
    out[OUT_THETA + b * 6 + 0] = cc;
    out[OUT_THETA + b * 6 + 1] = -ssn;
    out[OUT_THETA + b * 6 + 2] = mtx;
    out[OUT_THETA + b * 6 + 3] = ssn;
    out[OUT_THETA + b * 6 + 4] = cc;
    out[OUT_THETA + b * 6 + 5] = mty;
}

extern "C" void kernel_launch(void* const* d_in, const int* in_sizes, int n_in,
                              void* d_out, int out_size, void* d_ws, size_t ws_size,
                              hipStream_t stream) {
    const float* x = (const float*)d_in[0];
    float* out = (float*)d_out;
    float* ws  = (float*)d_ws;
    dim3 g1(4, 64, 64);
    k1_blocks<<<g1, 256, 0, stream>>>(x, out, ws);
    k2_global<<<64, 256, 0, stream>>>(out, ws);
    k3_orient<<<64, 256, 0, stream>>>(out, ws);
    k4_theta<<<1, 64, 0, stream>>>(out, ws);
}